// Round 1
// baseline (443.007 us; speedup 1.0000x reference)
//
#include <hip/hip_runtime.h>

#define T_SEQ 512
#define HID 64
#define MB 16             // batch rows per block
#define NTHREADS 1024     // 16 waves: 0-7 layer1 (2 tiles), 8-15 layer2 (2 tiles)
// OPERAND-FLIPPED MFMA: A = weights (regs), B = h (LDS). D[gate-unit][batch].
// LAYER-SPLIT: L1 waves read {h1 x2} + x-in-REGS; L2 waves read {h1 x2, h2 x2}.
// R12 changes:
//  * x B-fragment lives in registers (only quad-0 slice has nonzero weights in
//    w1elem, so quads 1-3 may hold garbage). Kills the hfx b128 read (8/56 of
//    the post-barrier LDS burst), the x staging writes, and the LDS x section.
//    x rows are L3-resident; loads are issued one full step (~1800 cy) ahead.
//  * v_cvt_pk_bf16_f32 (HW RNE, 1 instr) replaces manual f2bf+shift packing.
//  * gate_h merges the sigma(f)/i*g reciprocals over a common denominator:
//    7 trans instead of 8 per call.
//  * s_setprio(1) around the MFMA cluster (T5): favors lagging MFMA-phase
//    waves over waves already in their gate phase.
// Strides: BOTH 104 shorts = 52 dw == 20 mod 32 (20=4*5, 5 odd -> full bank
// spread, 2-way max). R10's A2STR=72 (36 dw == 4 mod 32) was an 8-way bug.
// R11 lesson: 4-tile waves (64 VGPR of weights) spill -> 2 tiles/wave max.
#define A1STR 104
#define A2STR 104

typedef __attribute__((ext_vector_type(8))) short short8;
typedef __attribute__((ext_vector_type(4))) float floatx4;
typedef float floatx4u __attribute__((ext_vector_type(4), aligned(4)));

#define LOG2E 1.4426950408889634f

__device__ __forceinline__ short f2bf_rne(float v) {
  unsigned u = __float_as_uint(v);
  return (short)((u + 0x7FFFu + ((u >> 16) & 1u)) >> 16);
}
__device__ __forceinline__ float rcp_(float x) { return __builtin_amdgcn_rcpf(x); }
__device__ __forceinline__ float exp2_(float x) { return __builtin_amdgcn_exp2f(x); }

// one-instruction RNE pack of two f32 -> 2x bf16 (no builtin on gfx950;
// register-only asm, no memory ordering hazards)
__device__ __forceinline__ unsigned cvt_pk_bf16(float lo, float hi) {
  unsigned r;
  asm("v_cvt_pk_bf16_f32 %0, %1, %2" : "=v"(r) : "v"(lo), "v"(hi));
  return r;
}

// gates pre-scaled: p[0,1,3] by LOG2E, p[2] by 2*LOG2E. rcp-fused, with the
// f-rcp and ig-rcp merged over a common denominator (7 trans, was 8):
//   t1 = (1+A)(G+1); t2 = (1+F)
//   c  = (c*t1 + (G-1)*t2) * rcp(t1*t2)     [== c/(1+F) + (G-1)/t1]
//   h  = (C-1) * rcp((1+O)(C+1))
__device__ __forceinline__ float gate_h(const floatx4 p, float& c) {
  float A = exp2_(-p[0]);
  float F = exp2_(-p[1]);
  float G = exp2_(p[2]);
  float O = exp2_(-p[3]);
  float t1 = (1.f + A) * (G + 1.f);
  float t2 = 1.f + F;
  float num = c * t1 + (G - 1.f) * t2;
  c = num * rcp_(t1 * t2);
  float C = exp2_((2.f * LOG2E) * c);
  return (C - 1.f) * rcp_((1.f + O) * (C + 1.f));
}

// build x B-fragment: 7 bf16 + zero pad (only quad-0 lanes' content matters)
__device__ __forceinline__ short8 xcvt(floatx4 lo, float x4, float x5, float x6) {
  union { unsigned u[4]; short8 s; } r;
  r.u[0] = cvt_pk_bf16(lo[0], lo[1]);
  r.u[1] = cvt_pk_bf16(lo[2], lo[3]);
  r.u[2] = cvt_pk_bf16(x4, x5);
  r.u[3] = cvt_pk_bf16(x6, 0.f);
  return r.s;
}

// unit stored at LDS h-position p
__device__ __forceinline__ int uofp(int p) {
  return (p & ~7) + ((p & 7) >> 1) + ((p & 1) << 2);
}

// Layer-1 weight at A-frag k-slot (K1=96): k<64 pairs h1 positions, 64..70 x
__device__ __forceinline__ short w1elem(int k, int n, float wsc,
                                        const float* __restrict__ Wih0,
                                        const float* __restrict__ Whh0) {
  float v;
  if      (k < 64) { v = Whh0[n*64 + uofp(k)]; }
  else if (k < 71) { v = Wih0[n*7 + (k - 64)]; }
  else return (short)0;
  return f2bf_rne(v * wsc);
}
// Layer-2 weight (K2=128): k<64 pairs h1 positions, 64..127 pairs h2 positions
__device__ __forceinline__ short w2elem(int k, int n, float wsc,
                                        const float* __restrict__ Wih1,
                                        const float* __restrict__ Whh1) {
  float v;
  if (k < 64) { v = Wih1[n*64 + uofp(k)]; }
  else        { v = Whh1[n*64 + uofp(k - 64)]; }
  return f2bf_rne(v * wsc);
}

// A = weights (first arg), B = h (second arg)
#define MFMA(A, B, C) __builtin_amdgcn_mfma_f32_16x16x32_bf16((A), (B), (C), 0, 0, 0)

__global__ __launch_bounds__(NTHREADS, 4) void lstm_fused(
    const float* __restrict__ x,
    const float* __restrict__ Wih0, const float* __restrict__ Whh0,
    const float* __restrict__ bih0, const float* __restrict__ bhh0,
    const float* __restrict__ Wih1, const float* __restrict__ Whh1,
    const float* __restrict__ bih1, const float* __restrict__ bhh1,
    const float* __restrict__ Wfc,  const float* __restrict__ bfc,
    float* __restrict__ out)
{
  __shared__ __align__(16) short A1[2][MB][A1STR];
  __shared__ __align__(16) short A2[2][MB][A2STR];
  __shared__ float h2f[MB][HID + 4];

  const int tid  = threadIdx.x;
  const int lane = tid & 63;
  const int wave = tid >> 6;           // 0..15
  const int wl   = wave & 7;           // index within layer group
  const bool isL1 = wave < 8;
  const int l15  = lane & 15;          // batch column
  const int quad = lane >> 4;
  const int quad8= quad * 8;
  const int g4   = l15 & 3;
  const int b0   = blockIdx.x * MB;
  const int u0   = wl*8 + quad;        // tile-0 owned unit
  const int u1   = u0 + 4;             // tile-1 owned unit
  const int hpos = wl*8 + 2*quad;      // packed h position (shorts, even)
  const int n0   = g4*64 + (wl*8 + (l15 >> 2));   // tile-0 weight row
  const int n1   = n0 + 4;                        // tile-1 weight row
  const float wsc = (g4 == 2) ? 2.f * LOG2E : LOG2E;

  // ---- zero both staging buffers (h(-1) = 0) ----
  for (int i = tid; i < 2*MB*A1STR/2; i += NTHREADS) ((unsigned*)A1)[i] = 0u;
  for (int i = tid; i < 2*MB*A2STR/2; i += NTHREADS) ((unsigned*)A2)[i] = 0u;

  // ---- biases for owned units (this thread's layer) ----
  const float* bi_ = isL1 ? bih0 : bih1;
  const float* bh_ = isL1 ? bhh0 : bhh1;
  floatx4 bia, bib;
  #pragma unroll
  for (int g = 0; g < 4; ++g) {
    float ws = (g == 2) ? 2.f * LOG2E : LOG2E;
    bia[g] = (bi_[g*64 + u0] + bh_[g*64 + u0]) * ws;
    bib[g] = (bi_[g*64 + u1] + bh_[g*64 + u1]) * ws;
  }

  // ---- x B-fragment in registers: lane reads its own batch row (l15).
  // Rows are 28 B / step, 14336 B apart; L3-resident. Quads 1-3 duplicate
  // quad-0's addresses (harmless: their kslot-2 weights are all zero).
  const float* xrow = x + (size_t)(b0 + l15) * (T_SEQ * 7);
  short8 xfrag = {};
  if (isL1) {
    floatx4 lo = *(const floatx4u*)xrow;
    xfrag = xcvt(lo, xrow[4], xrow[5], xrow[6]);
  }

  // ---- weight A-fragments (per layer group; tiles a/b) ----
  short8 WA[4], WB[4];
  if (isL1) {
    #pragma unroll
    for (int ks = 0; ks < 3; ++ks) {
      short8 fa, fb;
      #pragma unroll
      for (int jj = 0; jj < 8; ++jj) {
        fa[jj] = w1elem(ks*32 + quad8 + jj, n0, wsc, Wih0, Whh0);
        fb[jj] = w1elem(ks*32 + quad8 + jj, n1, wsc, Wih0, Whh0);
      }
      WA[ks] = fa; WB[ks] = fb;
    }
  } else {
    #pragma unroll
    for (int ks = 0; ks < 4; ++ks) {
      short8 fa, fb;
      #pragma unroll
      for (int jj = 0; jj < 8; ++jj) {
        fa[jj] = w2elem(ks*32 + quad8 + jj, n0, wsc, Wih1, Whh1);
        fb[jj] = w2elem(ks*32 + quad8 + jj, n1, wsc, Wih1, Whh1);
      }
      WA[ks] = fa; WB[ks] = fb;
    }
  }
  __syncthreads();

  float ca = 0.f, cb = 0.f;   // c-state for owned (layer, unit) pair

  // At entry of STEP_FULL(.,.,IT): xfrag holds x(IT); the step prefetches
  // x(IT+1) (clamped) and converts it after the MFMAs+gates (vmcnt covered
  // by ~a full step of work).
#define STEP_FULL(CUR, NXT, IT)                                              \
  {                                                                          \
    if (isL1) {                                                              \
      int xt_ = (IT) + 1; if (xt_ > T_SEQ - 1) xt_ = T_SEQ - 1;              \
      const float* xp_ = xrow + 7 * xt_;                                     \
      floatx4 nlo = *(const floatx4u*)xp_;                                   \
      float nx4 = xp_[4], nx5 = xp_[5], nx6 = xp_[6];                        \
      short8 hf0 = *(const short8*)&A1[CUR][l15][     quad8];                \
      short8 hf1 = *(const short8*)&A1[CUR][l15][32 + quad8];                \
      floatx4 pa = bia, pb = bib;                                            \
      __builtin_amdgcn_s_setprio(1);                                         \
      pa = MFMA(WA[0], hf0, pa);  pb = MFMA(WB[0], hf0, pb);                 \
      pa = MFMA(WA[1], hf1, pa);  pb = MFMA(WB[1], hf1, pb);                 \
      pa = MFMA(WA[2], xfrag, pa); pb = MFMA(WB[2], xfrag, pb);              \
      __builtin_amdgcn_s_setprio(0);                                         \
      float ha = gate_h(pa, ca);                                             \
      float hb = gate_h(pb, cb);                                             \
      *(unsigned*)&A1[NXT][l15][hpos] = cvt_pk_bf16(ha, hb);                 \
      xfrag = xcvt(nlo, nx4, nx5, nx6);                                      \
    } else {                                                                 \
      short8 hf0 = *(const short8*)&A1[CUR][l15][     quad8];                \
      short8 hf1 = *(const short8*)&A1[CUR][l15][32 + quad8];                \
      short8 h20 = *(const short8*)&A2[CUR][l15][     quad8];                \
      short8 h21 = *(const short8*)&A2[CUR][l15][32 + quad8];                \
      floatx4 pa = bia, pb = bib;                                            \
      __builtin_amdgcn_s_setprio(1);                                         \
      pa = MFMA(WA[0], hf0, pa);  pb = MFMA(WB[0], hf0, pb);                 \
      pa = MFMA(WA[1], hf1, pa);  pb = MFMA(WB[1], hf1, pb);                 \
      pa = MFMA(WA[2], h20, pa);  pb = MFMA(WB[2], h20, pb);                 \
      pa = MFMA(WA[3], h21, pa);  pb = MFMA(WB[3], h21, pb);                 \
      __builtin_amdgcn_s_setprio(0);                                         \
      float ha = gate_h(pa, ca);                                             \
      float hb = gate_h(pb, cb);                                             \
      *(unsigned*)&A2[NXT][l15][hpos] = cvt_pk_bf16(ha, hb);                 \
    }                                                                        \
    __syncthreads();                                                         \
  }

  // ---- it = 0: L1 only (A2[1] keeps zeros = h2(-1)) ----
  {
    if (isL1) {
      const float* xp_ = xrow + 7;
      floatx4 nlo = *(const floatx4u*)xp_;
      float nx4 = xp_[4], nx5 = xp_[5], nx6 = xp_[6];
      short8 hf0 = *(const short8*)&A1[0][l15][     quad8];
      short8 hf1 = *(const short8*)&A1[0][l15][32 + quad8];
      floatx4 pa = bia, pb = bib;
      pa = MFMA(WA[0], hf0, pa);  pb = MFMA(WB[0], hf0, pb);
      pa = MFMA(WA[1], hf1, pa);  pb = MFMA(WB[1], hf1, pb);
      pa = MFMA(WA[2], xfrag, pa); pb = MFMA(WB[2], xfrag, pb);
      float ha = gate_h(pa, ca);
      float hb = gate_h(pb, cb);
      *(unsigned*)&A1[1][l15][hpos] = cvt_pk_bf16(ha, hb);
      xfrag = xcvt(nlo, nx4, nx5, nx6);
    }
    __syncthreads();
  }

  // ---- main: it = 1..510, two steps per trip ----
  #pragma unroll 1
  for (int k = 0; k < 255; ++k) {
    STEP_FULL(1, 0, 2*k + 1)
    STEP_FULL(0, 1, 2*k + 2)
  }
  // ---- it = 511 ----
  STEP_FULL(1, 0, 511)

  // ---- it = 512: L2 only; write final h2 as f32 (natural unit index) ----
  {
    if (!isL1) {
      short8 hf0 = *(const short8*)&A1[0][l15][     quad8];
      short8 hf1 = *(const short8*)&A1[0][l15][32 + quad8];
      short8 h20 = *(const short8*)&A2[0][l15][     quad8];
      short8 h21 = *(const short8*)&A2[0][l15][32 + quad8];
      floatx4 pa = bia, pb = bib;
      pa = MFMA(WA[0], hf0, pa);  pb = MFMA(WB[0], hf0, pb);
      pa = MFMA(WA[1], hf1, pa);  pb = MFMA(WB[1], hf1, pb);
      pa = MFMA(WA[2], h20, pa);  pb = MFMA(WB[2], h20, pb);
      pa = MFMA(WA[3], h21, pa);  pb = MFMA(WB[3], h21, pb);
      h2f[l15][u0] = gate_h(pa, ca);
      h2f[l15][u1] = gate_h(pb, cb);
    }
    __syncthreads();
  }

  // ---- final FC ----
  if (tid < MB * 4) {
    int bbf = tid >> 2, o = tid & 3;
    float acc = bfc[o];
    #pragma unroll 8
    for (int kk = 0; kk < HID; ++kk) acc += h2f[bbf][kk] * Wfc[o*HID + kk];
    out[(size_t)(b0 + bbf) * 4 + o] = acc;
  }
}

extern "C" void kernel_launch(void* const* d_in, const int* in_sizes, int n_in,
                              void* d_out, int out_size, void* d_ws, size_t ws_size,
                              hipStream_t stream) {
  const float* x    = (const float*)d_in[0];
  const float* Wih0 = (const float*)d_in[1];
  const float* Whh0 = (const float*)d_in[2];
  const float* bih0 = (const float*)d_in[3];
  const float* bhh0 = (const float*)d_in[4];
  const float* Wih1 = (const float*)d_in[5];
  const float* Whh1 = (const float*)d_in[6];
  const float* bih1 = (const float*)d_in[7];
  const float* bhh1 = (const float*)d_in[8];
  const float* Wfc  = (const float*)d_in[9];
  const float* bfc  = (const float*)d_in[10];
  (void)d_ws; (void)ws_size; (void)n_in; (void)out_size;

  const int B = in_sizes[0] / (T_SEQ * 7);   // 4096
  dim3 grid(B / MB);
  lstm_fused<<<grid, NTHREADS, 0, stream>>>(x, Wih0, Whh0, bih0, bhh0,
                                            Wih1, Whh1, bih1, bhh1, Wfc, bfc,
                                            (float*)d_out);
}

// Round 3
// 427.389 us; speedup vs baseline: 1.0365x; 1.0365x over previous
//
#include <hip/hip_runtime.h>

#define T_SEQ 512
#define HID 64
#define MB 16             // batch rows per block
#define NTHREADS 1024     // 16 waves: 0-7 layer1 (2 tiles), 8-15 layer2 (2 tiles)
// OPERAND-FLIPPED MFMA: A = weights (regs), B = h (LDS). D[gate-unit][batch].
// LAYER-SPLIT: L1 waves read {h1 x2, x} = 3 b128; L2 waves read {h1 x2, h2 x2} = 4.
// Both tiles of a wave share B-fragments -> 56 b128/CU-iter.
// UNIT PERMUTATION: LDS position p holds unit U(p) = (p&~7)+((p&7)>>1)+((p&1)<<2)
// -> thread (wl,quad) owns units at adjacent positions: single packed b32 h-store.
// Strides: BOTH 104 shorts = 52 dw == 20 mod 32 (20=4*5, 5 odd -> full bank
// spread, 2-way max). R10's A2STR=72 (36 dw == 4 mod 32) was an 8-way bug.
// R11 lesson: 4-tile waves (64 VGPR of weights) spill -> 2 tiles/wave max.
// R12 lesson (A/B decomposition): x-in-registers + setprio REGRESSED (+11us)
//   while cvt_pk pack + merged-rcp gate genuinely cut VALU (-128cy/step,
//   VALUBusy 63.6->55.3). This version = R0 structure + the two verified VALU
//   cuts; x staged via LDS again (full-step prefetch distance, 1 load/lane)
//   but PAIR-PACKED: 4 lanes/row write one b32 each (cvt_pk) instead of 7
//   lanes writing b16 (kills same-dword sub-word write serialization).
// R13: previous submission died on a harness infra error (Trio nursery).
//   Same kernel; added a __syncthreads between LDS zeroing and initial
//   x-stage to close a latent (R0-era) zero-vs-stage race.
#define A1STR 104
#define A2STR 104

typedef __attribute__((ext_vector_type(8))) short short8;
typedef __attribute__((ext_vector_type(4))) float floatx4;

#define LOG2E 1.4426950408889634f

__device__ __forceinline__ short f2bf_rne(float v) {
  unsigned u = __float_as_uint(v);
  return (short)((u + 0x7FFFu + ((u >> 16) & 1u)) >> 16);
}
__device__ __forceinline__ float rcp_(float x) { return __builtin_amdgcn_rcpf(x); }
__device__ __forceinline__ float exp2_(float x) { return __builtin_amdgcn_exp2f(x); }

// one-instruction RNE pack of two f32 -> 2x bf16 (no builtin on gfx950;
// register-only asm, no memory ordering hazards)
__device__ __forceinline__ unsigned cvt_pk_bf16(float lo, float hi) {
  unsigned r;
  asm("v_cvt_pk_bf16_f32 %0, %1, %2" : "=v"(r) : "v"(lo), "v"(hi));
  return r;
}

// gates pre-scaled: p[0,1,3] by LOG2E, p[2] by 2*LOG2E. rcp-fused, with the
// f-rcp and ig-rcp merged over a common denominator (7 trans, was 8):
//   t1 = (1+A)(G+1); t2 = (1+F)
//   c  = (c*t1 + (G-1)*t2) * rcp(t1*t2)     [== c/(1+F) + (G-1)/t1]
//   h  = (C-1) * rcp((1+O)(C+1))
// Verified in R12: same absmax (2^-10) as the unmerged form.
__device__ __forceinline__ float gate_h(const floatx4 p, float& c) {
  float A = exp2_(-p[0]);
  float F = exp2_(-p[1]);
  float G = exp2_(p[2]);
  float O = exp2_(-p[3]);
  float t1 = (1.f + A) * (G + 1.f);
  float t2 = 1.f + F;
  float num = c * t1 + (G - 1.f) * t2;
  c = num * rcp_(t1 * t2);
  float C = exp2_((2.f * LOG2E) * c);
  return (C - 1.f) * rcp_((1.f + O) * (C + 1.f));
}

// unit stored at LDS h-position p
__device__ __forceinline__ int uofp(int p) {
  return (p & ~7) + ((p & 7) >> 1) + ((p & 1) << 2);
}

// Layer-1 weight at A-frag k-slot (K1=96): k<64 pairs h1 positions, 64..70 x
__device__ __forceinline__ short w1elem(int k, int n, float wsc,
                                        const float* __restrict__ Wih0,
                                        const float* __restrict__ Whh0) {
  float v;
  if      (k < 64) { v = Whh0[n*64 + uofp(k)]; }
  else if (k < 71) { v = Wih0[n*7 + (k - 64)]; }
  else return (short)0;
  return f2bf_rne(v * wsc);
}
// Layer-2 weight (K2=128): k<64 pairs h1 positions, 64..127 pairs h2 positions
__device__ __forceinline__ short w2elem(int k, int n, float wsc,
                                        const float* __restrict__ Wih1,
                                        const float* __restrict__ Whh1) {
  float v;
  if (k < 64) { v = Wih1[n*64 + uofp(k)]; }
  else        { v = Whh1[n*64 + uofp(k - 64)]; }
  return f2bf_rne(v * wsc);
}

// A = weights (first arg), B = h (second arg)
#define MFMA(A, B, C) __builtin_amdgcn_mfma_f32_16x16x32_bf16((A), (B), (C), 0, 0, 0)

__global__ __launch_bounds__(NTHREADS, 4) void lstm_fused(
    const float* __restrict__ x,
    const float* __restrict__ Wih0, const float* __restrict__ Whh0,
    const float* __restrict__ bih0, const float* __restrict__ bhh0,
    const float* __restrict__ Wih1, const float* __restrict__ Whh1,
    const float* __restrict__ bih1, const float* __restrict__ bhh1,
    const float* __restrict__ Wfc,  const float* __restrict__ bfc,
    float* __restrict__ out)
{
  __shared__ __align__(16) short A1[2][MB][A1STR];
  __shared__ __align__(16) short A2[2][MB][A2STR];
  __shared__ float h2f[MB][HID + 4];

  const int tid  = threadIdx.x;
  const int lane = tid & 63;
  const int wave = tid >> 6;           // 0..15
  const int wl   = wave & 7;           // index within layer group
  const bool isL1 = wave < 8;
  const int l15  = lane & 15;          // batch column
  const int quad = lane >> 4;
  const int quad8= quad * 8;
  const int g4   = l15 & 3;
  const int b0   = blockIdx.x * MB;
  const int u0   = wl*8 + quad;        // tile-0 owned unit
  const int u1   = u0 + 4;             // tile-1 owned unit
  const int hpos = wl*8 + 2*quad;      // packed h position (shorts, even)
  const int n0   = g4*64 + (wl*8 + (l15 >> 2));   // tile-0 weight row
  const int n1   = n0 + 4;                        // tile-1 weight row
  const float wsc = (g4 == 2) ? 2.f * LOG2E : LOG2E;

  // ---- zero both staging buffers (h(-1) = 0, x pad = 0) ----
  for (int i = tid; i < 2*MB*A1STR/2; i += NTHREADS) ((unsigned*)A1)[i] = 0u;
  for (int i = tid; i < 2*MB*A2STR/2; i += NTHREADS) ((unsigned*)A2)[i] = 0u;
  __syncthreads();   // zeroing fully done before anyone stages x into A1[0]

  // ---- biases for owned units (this thread's layer) ----
  const float* bi_ = isL1 ? bih0 : bih1;
  const float* bh_ = isL1 ? bhh0 : bhh1;
  floatx4 bia, bib;
  #pragma unroll
  for (int g = 0; g < 4; ++g) {
    float ws = (g == 2) ? 2.f * LOG2E : LOG2E;
    bia[g] = (bi_[g*64 + u0] + bh_[g*64 + u0]) * ws;
    bib[g] = (bi_[g*64 + u1] + bh_[g*64 + u1]) * ws;
  }

  // ---- x staging: spread across all 8 L1 waves (2 batch rows each).
  // Pair-packed: lane xd2 in 0..3 owns x elements {2*xd2, 2*xd2+1} of its
  // row (element 7 is the zero pad; x[7] never touched -> no OOB). One
  // cvt_pk + one b32 LDS write per lane; prefetch distance = one full step.
  const int xd2  = lane & 31;          // 0..3 active
  const int xrow = 2*wl + (lane >> 5);
  const bool xact = isL1 && (xd2 < 4);
  const float* xbase = x + ((size_t)(b0 + xrow) * T_SEQ) * 7 + 2*xd2;
  float xc0 = 0.f, xc1 = 0.f;
  if (xact) {
    *(unsigned*)&A1[0][xrow][64 + 2*xd2] =
        cvt_pk_bf16(xbase[0], (xd2 < 3) ? xbase[1] : 0.f);
    xc0 = xbase[7];
    xc1 = (xd2 < 3) ? xbase[8] : 0.f;
  }

  // ---- weight A-fragments (per layer group; tiles a/b) ----
  short8 WA[4], WB[4];
  if (isL1) {
    #pragma unroll
    for (int ks = 0; ks < 3; ++ks) {
      short8 fa, fb;
      #pragma unroll
      for (int jj = 0; jj < 8; ++jj) {
        fa[jj] = w1elem(ks*32 + quad8 + jj, n0, wsc, Wih0, Whh0);
        fb[jj] = w1elem(ks*32 + quad8 + jj, n1, wsc, Wih0, Whh0);
      }
      WA[ks] = fa; WB[ks] = fb;
    }
  } else {
    #pragma unroll
    for (int ks = 0; ks < 4; ++ks) {
      short8 fa, fb;
      #pragma unroll
      for (int jj = 0; jj < 8; ++jj) {
        fa[jj] = w2elem(ks*32 + quad8 + jj, n0, wsc, Wih1, Whh1);
        fb[jj] = w2elem(ks*32 + quad8 + jj, n1, wsc, Wih1, Whh1);
      }
      WA[ks] = fa; WB[ks] = fb;
    }
  }
  __syncthreads();

  float ca = 0.f, cb = 0.f;   // c-state for owned (layer, unit) pair

#define STEP_X(NXT, XT)                                                      \
    if (xact) {                                                              \
      *(unsigned*)&A1[NXT][xrow][64 + 2*xd2] = cvt_pk_bf16(xc0, xc1);        \
      xc0 = xbase[7 * (XT)];                                                 \
      xc1 = (xd2 < 3) ? xbase[7 * (XT) + 1] : 0.f;                           \
    }

#define STEP_FULL(CUR, NXT, IT)                                              \
  {                                                                          \
    if (isL1) {                                                              \
      int xt_ = (IT) + 2; if (xt_ > T_SEQ - 1) xt_ = T_SEQ - 1;              \
      STEP_X(NXT, xt_)                                                       \
      short8 hf0 = *(const short8*)&A1[CUR][l15][     quad8];                \
      short8 hf1 = *(const short8*)&A1[CUR][l15][32 + quad8];                \
      short8 hfx = *(const short8*)&A1[CUR][l15][64 + quad8];                \
      floatx4 pa = bia, pb = bib;                                            \
      pa = MFMA(WA[0], hf0, pa);  pb = MFMA(WB[0], hf0, pb);                 \
      pa = MFMA(WA[1], hf1, pa);  pb = MFMA(WB[1], hf1, pb);                 \
      pa = MFMA(WA[2], hfx, pa);  pb = MFMA(WB[2], hfx, pb);                 \
      float ha = gate_h(pa, ca);                                             \
      float hb = gate_h(pb, cb);                                             \
      *(unsigned*)&A1[NXT][l15][hpos] = cvt_pk_bf16(ha, hb);                 \
    } else {                                                                 \
      short8 hf0 = *(const short8*)&A1[CUR][l15][     quad8];                \
      short8 hf1 = *(const short8*)&A1[CUR][l15][32 + quad8];                \
      short8 h20 = *(const short8*)&A2[CUR][l15][     quad8];                \
      short8 h21 = *(const short8*)&A2[CUR][l15][32 + quad8];                \
      floatx4 pa = bia, pb = bib;                                            \
      pa = MFMA(WA[0], hf0, pa);  pb = MFMA(WB[0], hf0, pb);                 \
      pa = MFMA(WA[1], hf1, pa);  pb = MFMA(WB[1], hf1, pb);                 \
      pa = MFMA(WA[2], h20, pa);  pb = MFMA(WB[2], h20, pb);                 \
      pa = MFMA(WA[3], h21, pa);  pb = MFMA(WB[3], h21, pb);                 \
      float ha = gate_h(pa, ca);                                             \
      float hb = gate_h(pb, cb);                                             \
      *(unsigned*)&A2[NXT][l15][hpos] = cvt_pk_bf16(ha, hb);                 \
    }                                                                        \
    __syncthreads();                                                         \
  }

  // ---- it = 0: L1 only (A2[1] keeps zeros = h2(-1)) ----
  {
    if (isL1) {
      STEP_X(1, 2)
      short8 hf0 = *(const short8*)&A1[0][l15][     quad8];
      short8 hf1 = *(const short8*)&A1[0][l15][32 + quad8];
      short8 hfx = *(const short8*)&A1[0][l15][64 + quad8];
      floatx4 pa = bia, pb = bib;
      pa = MFMA(WA[0], hf0, pa);  pb = MFMA(WB[0], hf0, pb);
      pa = MFMA(WA[1], hf1, pa);  pb = MFMA(WB[1], hf1, pb);
      pa = MFMA(WA[2], hfx, pa);  pb = MFMA(WB[2], hfx, pb);
      float ha = gate_h(pa, ca);
      float hb = gate_h(pb, cb);
      *(unsigned*)&A1[1][l15][hpos] = cvt_pk_bf16(ha, hb);
    }
    __syncthreads();
  }

  // ---- main: it = 1..510, two steps per trip ----
  #pragma unroll 1
  for (int k = 0; k < 255; ++k) {
    STEP_FULL(1, 0, 2*k + 1)
    STEP_FULL(0, 1, 2*k + 2)
  }
  // ---- it = 511 ----
  STEP_FULL(1, 0, 511)

  // ---- it = 512: L2 only; write final h2 as f32 (natural unit index) ----
  {
    if (!isL1) {
      short8 hf0 = *(const short8*)&A1[0][l15][     quad8];
      short8 hf1 = *(const short8*)&A1[0][l15][32 + quad8];
      short8 h20 = *(const short8*)&A2[0][l15][     quad8];
      short8 h21 = *(const short8*)&A2[0][l15][32 + quad8];
      floatx4 pa = bia, pb = bib;
      pa = MFMA(WA[0], hf0, pa);  pb = MFMA(WB[0], hf0, pb);
      pa = MFMA(WA[1], hf1, pa);  pb = MFMA(WB[1], hf1, pb);
      pa = MFMA(WA[2], h20, pa);  pb = MFMA(WB[2], h20, pb);
      pa = MFMA(WA[3], h21, pa);  pb = MFMA(WB[3], h21, pb);
      h2f[l15][u0] = gate_h(pa, ca);
      h2f[l15][u1] = gate_h(pb, cb);
    }
    __syncthreads();
  }

  // ---- final FC ----
  if (tid < MB * 4) {
    int bbf = tid >> 2, o = tid & 3;
    float acc = bfc[o];
    #pragma unroll 8
    for (int kk = 0; kk < HID; ++kk) acc += h2f[bbf][kk] * Wfc[o*HID + kk];
    out[(size_t)(b0 + bbf) * 4 + o] = acc;
  }
}

extern "C" void kernel_launch(void* const* d_in, const int* in_sizes, int n_in,
                              void* d_out, int out_size, void* d_ws, size_t ws_size,
                              hipStream_t stream) {
  const float* x    = (const float*)d_in[0];
  const float* Wih0 = (const float*)d_in[1];
  const float* Whh0 = (const float*)d_in[2];
  const float* bih0 = (const float*)d_in[3];
  const float* bhh0 = (const float*)d_in[4];
  const float* Wih1 = (const float*)d_in[5];
  const float* Whh1 = (const float*)d_in[6];
  const float* bih1 = (const float*)d_in[7];
  const float* bhh1 = (const float*)d_in[8];
  const float* Wfc  = (const float*)d_in[9];
  const float* bfc  = (const float*)d_in[10];
  (void)d_ws; (void)ws_size; (void)n_in; (void)out_size;

  const int B = in_sizes[0] / (T_SEQ * 7);   // 4096
  dim3 grid(B / MB);
  lstm_fused<<<grid, NTHREADS, 0, stream>>>(x, Wih0, Whh0, bih0, bhh0,
                                            Wih1, Whh1, bih1, bhh1, Wfc, bfc,
                                            (float*)d_out);
}